// Round 14
// baseline (285.119 us; speedup 1.0000x reference)
//
#include <hip/hip_runtime.h>
#include <hip/hip_bf16.h>
#include <stdint.h>

#define NB 32
#define NR 2048
#define NC 64
#define NO 64
#define NK 16

using bf16x8 = __attribute__((ext_vector_type(8))) short;
using f32x4  = __attribute__((ext_vector_type(4))) float;

// counted per-wave waits (rule #18: sched_barrier after the asm)
#define WAITVM(N) do { asm volatile("s_waitcnt vmcnt(" #N ")" ::: "memory"); \
                       __builtin_amdgcn_sched_barrier(0); } while (0)

__device__ __forceinline__ uint32_t f2bf(float f) {
  uint32_t u = __builtin_bit_cast(uint32_t, f);
  return (u + 0x7fffu + ((u >> 16) & 1u)) >> 16;  // RNE (bit math)
}
__device__ __forceinline__ uint32_t packbf2(float lo, float hi) {
  return f2bf(lo) | (f2bf(hi) << 16);
}
// HW pair conversion (v_cvt_pk_bf16_f32); memcpy because __hip_bfloat162 is
// not trivially copyable.
__device__ __forceinline__ uint32_t cvtpk2(float lo, float hi) {
  float2 v; v.x = lo; v.y = hi;
  __hip_bfloat162 h = __float22bfloat162_rn(v);
  uint32_t r;
  __builtin_memcpy(&r, &h, 4);
  return r;
}

// x[b][r][c] -> xbf[r][ks][mt][lane][e] bf16 (A-fragment order).
// Slot (lane,e) of frag (ks,mt) holds x[b = mt*16 + (lane&15)]
//                                     [c = ks*32 + (lane>>4)*8 + e].
// Same slot->c map is used for the B operand, so the HW k-order cancels.
__global__ __launch_bounds__(256) void make_xbf(const float* __restrict__ x,
                                                ushort* __restrict__ xbf) {
  __shared__ float tile[32][72];
  const int r = blockIdx.x, t = threadIdx.x;
  {
    const int b = t >> 3, c0 = (t & 7) << 3;
    const float* xp = x + ((size_t)b * NR + r) * NC + c0;
    *(float4*)&tile[b][c0] = *(const float4*)xp;
    *(float4*)&tile[b][c0 + 4] = *(const float4*)(xp + 4);
  }
  __syncthreads();
  {
    const int ks = t >> 7, mt = (t >> 6) & 1, l = t & 63;
    const int b = mt * 16 + (l & 15);
    const int cb = ks * 32 + (l >> 4) * 8;
    uint4 uv;
    uv.x = packbf2(tile[b][cb + 0], tile[b][cb + 1]);
    uv.y = packbf2(tile[b][cb + 2], tile[b][cb + 3]);
    uv.z = packbf2(tile[b][cb + 4], tile[b][cb + 5]);
    uv.w = packbf2(tile[b][cb + 6], tile[b][cb + 7]);
    *(uint4*)(xbf + (size_t)r * 2048 + t * 8) = uv;
  }
}

// MFMA GEMM, barrier-free, REG-STAGED conveyor (this round's single change):
// global_load_dwordx4 -> named reg banks RA/RB -> counted vmcnt -> ds_write_b128,
// replacing global_load_lds (theory: the direct-to-LDS DMA path caps per-CU
// outstanding requests at ~4KB -> 2.6 TB/s ceiling seen in R4..R13; plain
// loads are the m13-proven 6.3 TB/s path). LDS image, compute, epilogue,
// routing all byte-identical to R13.
// Half-step h = ti*2+ks (16 total). Invariant at top of h: buf[h&1] holds
// data(h); bank[(h+1)&1] holds data(h+1) in flight/arrived. Body: issue
// loads(h+2) into bank[h&1]; compute(h); WAITVM(8) retires data(h+1) while
// data(h+2)'s 8 loads stay in flight; ds_write data(h+1) -> buf[(h+1)&1].
__global__ __launch_bounds__(256, 2) void priors_gemm(const ushort* __restrict__ xbf,
                                                      const float* __restrict__ W,
                                                      ushort* __restrict__ priors) {
  __shared__ float ldsW[2][4][2048];   // [buf][wave][32c x 64o] fp32, 64KB
  __shared__ ushort ldsE[4][2048];     // [wave][32b x 64o] bf16, 16KB epilogue
  const int w = threadIdx.x >> 6, lane = threadIdx.x & 63;
  const int g = lane >> 4, col = lane & 15;
  const int kq = blockIdx.x & 3, rblk = blockIdx.x >> 2;  // consecutive bids share rblk
  const int k = kq * 4 + w;
  const float* wbase = W + ((size_t)(k * NR + rblk * 8)) * 4096;

  f32x4 acc[2][4];
  float4 RA[8], RB[8];

  // per-lane source addresses (bank-spread swizzle, same LDS image as R13)
  int srcoff[8];
#pragma unroll
  for (int i = 0; i < 8; ++i) {
    const int c = i * 4 + (lane >> 4);
    const int gc = c >> 3;
    const int jj = (lane & 15) ^ (gc & 3) ^ ((gc >> 1) << 2);
    srcoff[i] = c * 64 + jj * 4;
  }

#define LOADW(BANK, H)                                                        \
  do {                                                                        \
    const float* src_ = wbase + (size_t)(H) * 2048;                           \
    _Pragma("unroll") for (int i_ = 0; i_ < 8; ++i_)                          \
      BANK[i_] = *(const float4*)(src_ + srcoff[i_]);                         \
  } while (0)

#define DSWRITE(BANK, BUF)                                                    \
  do {                                                                        \
    float* dst_ = &ldsW[BUF][w][0] + lane * 4;                                \
    _Pragma("unroll") for (int i_ = 0; i_ < 8; ++i_)                          \
      *(float4*)(dst_ + i_ * 256) = BANK[i_];                                 \
  } while (0)

  auto compute = [&](bf16x8 af0, bf16x8 af1, int buf) {
    const float* pw = &ldsW[buf][w][0];
#pragma unroll
    for (int nt = 0; nt < 4; ++nt) {
      const int oo = (nt * 16 + col) ^ ((g & 3) << 2) ^ ((g >> 1) << 4);
      float f[8];
#pragma unroll
      for (int e = 0; e < 8; ++e) f[e] = pw[(g * 8 + e) * 64 + oo];
      uint4 uv;
      uv.x = cvtpk2(f[0], f[1]);
      uv.y = cvtpk2(f[2], f[3]);
      uv.z = cvtpk2(f[4], f[5]);
      uv.w = cvtpk2(f[6], f[7]);
      bf16x8 bfr = __builtin_bit_cast(bf16x8, uv);
      acc[0][nt] = __builtin_amdgcn_mfma_f32_16x16x32_bf16(af0, bfr, acc[0][nt], 0, 0, 0);
      acc[1][nt] = __builtin_amdgcn_mfma_f32_16x16x32_bf16(af1, bfr, acc[1][nt], 0, 0, 0);
    }
  };

  auto epilogue = [&](int rr) {
    // C/D layout (HW-verified m89/m91): col = lane&15, row = (lane>>4)*4 + reg.
    ushort* ep = &ldsE[w][0];
#pragma unroll
    for (int mt = 0; mt < 2; ++mt)
#pragma unroll
      for (int nt = 0; nt < 4; ++nt)
#pragma unroll
        for (int rp = 0; rp < 2; ++rp) {
          uint32_t u = cvtpk2(acc[mt][nt][rp * 2], acc[mt][nt][rp * 2 + 1]);
          const int row0 = mt * 16 + g * 4 + rp * 2;
          ep[(row0 + 0) * 64 + nt * 16 + col] = (ushort)u;
          ep[(row0 + 1) * 64 + nt * 16 + col] = (ushort)(u >> 16);
        }
    ushort* pp = priors + ((size_t)(k * NR + rblk * 8 + rr)) * 2048;
#pragma unroll
    for (int i = 0; i < 4; ++i) {
      uint4 v = *(const uint4*)(ep + lane * 8 + i * 512);
      *(uint4*)(pp + lane * 8 + i * 512) = v;
    }
  };

  // prologue: h=0 into buf0 (one exposed latency), h=1 in flight in RB
  LOADW(RA, 0);
  WAITVM(0);
  DSWRITE(RA, 0);
  LOADW(RB, 1);

  for (int ti = 0; ti < 8; ++ti) {
    const size_t r = rblk * 8 + ti;
    const int h0 = ti * 2;
    // A-frags for this ti (compiler's pre-MFMA wait retires these + data(h0+1),
    // leaving the h0+2 loads in flight)
    bf16x8 a00 = *(const bf16x8*)(xbf + ((r * 2 + 0) * 2 + 0) * 512 + lane * 8);
    bf16x8 a10 = *(const bf16x8*)(xbf + ((r * 2 + 0) * 2 + 1) * 512 + lane * 8);
    bf16x8 a01 = *(const bf16x8*)(xbf + ((r * 2 + 1) * 2 + 0) * 512 + lane * 8);
    bf16x8 a11 = *(const bf16x8*)(xbf + ((r * 2 + 1) * 2 + 1) * 512 + lane * 8);
#pragma unroll
    for (int mt = 0; mt < 2; ++mt)
#pragma unroll
      for (int nt = 0; nt < 4; ++nt) acc[mt][nt] = f32x4{0.f, 0.f, 0.f, 0.f};

    // even half-step h0: buf0 holds data(h0); RB holds data(h0+1)
    if (h0 + 2 < 16) LOADW(RA, h0 + 2);
    compute(a00, a10, 0);
    WAITVM(8);                 // retire data(h0+1); data(h0+2) stays in flight
    DSWRITE(RB, 1);

    // odd half-step h0+1: buf1 holds data(h0+1); RA holds data(h0+2)
    if (h0 + 3 < 16) LOADW(RB, h0 + 3);
    compute(a01, a11, 1);
    if (h0 + 2 < 16) {
      WAITVM(8);               // retire data(h0+2); data(h0+3) stays in flight
      DSWRITE(RA, 0);
    }
    epilogue(ti);
  }
}

// Routing pass (unchanged). Block per kb (k = kb>>5, b = kb&31).
// priors layout [k][r][b][o]. Lane: g = lane/8, sl = lane%8.
// PASS==1: phase A computes o0 = squash(mean_r p) in-block (priors read #1);
//          phase B: l = a_r = p.o0, stores a_r, writes o1 (priors read #2, L3-hot).
// PASS==2: l = a_r + p.o1; writes final output.
template <int PASS>
__global__ __launch_bounds__(256) void routing(const __hip_bfloat16* __restrict__ priors,
                                               float* __restrict__ Abuf,
                                               const float* __restrict__ o_prev,
                                               float* __restrict__ o_out) {
  __shared__ float o_lds[64];
  __shared__ float red_num[4][8][8];
  __shared__ float red_den[4];
  const int kb = blockIdx.x;
  const int k = kb >> 5, b = kb & 31;
  const int tid = threadIdx.x, w = tid >> 6, lane = tid & 63;
  const int g = lane >> 3, sl = lane & 7;
  const int rsub = w * 8 + g;
  const __hip_bfloat16* pbase = priors + (size_t)k * NR * NB * NO + (size_t)b * NO;
  float* ab = Abuf + (size_t)kb * NR;

  if (PASS == 1) {
    float sum[8];
#pragma unroll
    for (int j = 0; j < 8; ++j) sum[j] = 0.f;
    for (int it = 0; it < NR / 32; ++it) {
      const int r = it * 32 + rsub;
      uint4 pv = *(const uint4*)(pbase + (size_t)r * (NB * NO) + sl * 8);
      sum[0] += __builtin_bit_cast(float, pv.x << 16);
      sum[1] += __builtin_bit_cast(float, pv.x & 0xffff0000u);
      sum[2] += __builtin_bit_cast(float, pv.y << 16);
      sum[3] += __builtin_bit_cast(float, pv.y & 0xffff0000u);
      sum[4] += __builtin_bit_cast(float, pv.z << 16);
      sum[5] += __builtin_bit_cast(float, pv.z & 0xffff0000u);
      sum[6] += __builtin_bit_cast(float, pv.w << 16);
      sum[7] += __builtin_bit_cast(float, pv.w & 0xffff0000u);
    }
#pragma unroll
    for (int m = 8; m < 64; m <<= 1)
#pragma unroll
      for (int j = 0; j < 8; ++j) sum[j] += __shfl_xor(sum[j], m, 64);
    if (lane < 8) {
#pragma unroll
      for (int j = 0; j < 8; ++j) red_num[w][lane][j] = sum[j];
    }
    __syncthreads();
    if (tid < 64) {
      const int s_ = tid >> 3, j_ = tid & 7;
      float sv = (red_num[0][s_][j_] + red_num[1][s_][j_] +
                  red_num[2][s_][j_] + red_num[3][s_][j_]) * (1.f / (float)NR);
      float sq = sv * sv;
#pragma unroll
      for (int m = 1; m < 64; m <<= 1) sq += __shfl_xor(sq, m, 64);
      o_lds[tid] = (sq / (1.f + sq)) * rsqrtf(sq) * sv;  // squash
    }
    __syncthreads();
  } else {
    if (tid < 64) o_lds[tid] = o_prev[kb * 64 + tid];
    __syncthreads();
  }

  float os[8];
#pragma unroll
  for (int j = 0; j < 8; ++j) os[j] = o_lds[sl * 8 + j];

  float num[8];
#pragma unroll
  for (int j = 0; j < 8; ++j) num[j] = 0.f;
  float den = 0.f;

  for (int it = 0; it < NR / 32; ++it) {
    const int r = it * 32 + rsub;
    uint4 pv = *(const uint4*)(pbase + (size_t)r * (NB * NO) + sl * 8);
    float f[8];
    f[0] = __builtin_bit_cast(float, pv.x << 16);
    f[1] = __builtin_bit_cast(float, pv.x & 0xffff0000u);
    f[2] = __builtin_bit_cast(float, pv.y << 16);
    f[3] = __builtin_bit_cast(float, pv.y & 0xffff0000u);
    f[4] = __builtin_bit_cast(float, pv.z << 16);
    f[5] = __builtin_bit_cast(float, pv.z & 0xffff0000u);
    f[6] = __builtin_bit_cast(float, pv.w << 16);
    f[7] = __builtin_bit_cast(float, pv.w & 0xffff0000u);

    float d = 0.f;
#pragma unroll
    for (int j = 0; j < 8; ++j) d = fmaf(f[j], os[j], d);
#pragma unroll
    for (int m = 1; m < 8; m <<= 1) d += __shfl_xor(d, m, 64);

    float lg;
    if (PASS == 1) {
      lg = d;
      if (sl == 0) ab[r] = d;
    } else {
      lg = d + ab[r];
    }
    float e = __expf(lg);  // |lg| << 1, no max-subtraction needed
    den += e;
#pragma unroll
    for (int j = 0; j < 8; ++j) num[j] = fmaf(e, f[j], num[j]);
  }

#pragma unroll
  for (int m = 8; m < 64; m <<= 1) {
    den += __shfl_xor(den, m, 64);
#pragma unroll
    for (int j = 0; j < 8; ++j) num[j] += __shfl_xor(num[j], m, 64);
  }
  if (lane < 8) {
#pragma unroll
    for (int j = 0; j < 8; ++j) red_num[w][lane][j] = num[j];
    if (lane == 0) red_den[w] = den;
  }
  __syncthreads();

  if (tid < 64) {
    const int s_ = tid >> 3, j_ = tid & 7;
    float nm = red_num[0][s_][j_] + red_num[1][s_][j_] + red_num[2][s_][j_] + red_num[3][s_][j_];
    float dn = red_den[0] + red_den[1] + red_den[2] + red_den[3];
    float sv = nm / dn;
    float sq = sv * sv;
#pragma unroll
    for (int m = 1; m < 64; m <<= 1) sq += __shfl_xor(sq, m, 64);
    float ov = (sq / (1.f + sq)) * rsqrtf(sq) * sv;
    o_out[kb * 64 + tid] = ov;
  }
}

extern "C" void kernel_launch(void* const* d_in, const int* in_sizes, int n_in,
                              void* d_out, int out_size, void* d_ws, size_t ws_size,
                              hipStream_t stream) {
  const float* x = (const float*)d_in[0];          // [B][R][CIN]
  const float* W = (const float*)d_in[1];          // [K][R][CIN][COUT]
  float* out = (float*)d_out;                      // [K][B][COUT]
  char* ws = (char*)d_ws;

  size_t off = 0;
  ushort* xbf = (ushort*)(ws + off);               off += (size_t)NR * 2048 * 2;           // 8 MB
  ushort* priors = (ushort*)(ws + off);            off += (size_t)NK * NR * NB * NO * 2;   // 128 MB
  float* o1 = (float*)(ws + off);                  off += (size_t)NK * NB * NO * 4;        // 128 KB
  float* Abuf = (float*)(ws + off);                off += (size_t)NK * NB * NR * 4;        // 4 MB

  make_xbf<<<NR, 256, 0, stream>>>(x, xbf);
  priors_gemm<<<(NR / 8) * (NK / 4), 256, 0, stream>>>(xbf, W, priors);
  routing<1><<<NK * NB, 256, 0, stream>>>((const __hip_bfloat16*)priors, Abuf, nullptr, o1);
  routing<2><<<NK * NB, 256, 0, stream>>>((const __hip_bfloat16*)priors, Abuf, o1, out);
}